// Round 15
// baseline (409.683 us; speedup 1.0000x reference)
//
#include <hip/hip_runtime.h>
#include <hip/hip_fp16.h>
#include <math.h>

typedef __attribute__((ext_vector_type(8))) _Float16 f16x8;
typedef __attribute__((ext_vector_type(2))) __fp16 fp16x2;
typedef __attribute__((ext_vector_type(4))) float f32x4;

constexpr int D = 256;           // feature dim (K of GEMM)
constexpr int H = 128;           // hidden dim
constexpr int KSTEPS = D / 32;   // 8 MFMA k-steps
constexpr int BM = 32;           // rows per tile (N = 300000 = 32 * 9375)
constexpr int NBLK = 256;        // persistent blocks (1 per CU)

union FragH { uint4 u; f16x8 f; };
union H2U { fp16x2 h; unsigned int u; };

__device__ __forceinline__ unsigned int pkrtz(float a, float b) {
  H2U r; r.h = __builtin_amdgcn_cvt_pkrtz(a, b); return r.u;
}
__device__ __forceinline__ void gload16(const void* g, void* l) {
  __builtin_amdgcn_global_load_lds(
      (const __attribute__((address_space(1))) unsigned int*)g,
      (__attribute__((address_space(3))) unsigned int*)l, 16, 0, 0);
}

// ---- init: zero d_out + Z accumulator --------------------------------------
extern "C" __global__ void __launch_bounds__(256)
k_init(float* __restrict__ out, int out_size, float* __restrict__ zacc)
{
  const int i = blockIdx.x * 256 + threadIdx.x;
  if (i < out_size) out[i] = 0.0f;
  if (i == 0) *zacc = 0.0f;
}

// ---- Pre-pack W1 into per-lane MFMA B-fragment order (fp16 RTN) ------------
// Index g = (kstep*8 + htile)*64 + lane; element j: K = kstep*32+(lane>>4)*8+j,
// N(col) = htile*16 + (lane&15).
extern "C" __global__ void __launch_bounds__(256)
k_pack(const float* __restrict__ W1, uint4* __restrict__ pw)
{
  const int g = blockIdx.x * 256 + threadIdx.x;       // 0..4095
  const int c = g >> 9, ht = (g >> 6) & 7, l = g & 63;
  const int kbase = c * 32 + (l >> 4) * 8;
  const int col = ht * 16 + (l & 15);
  unsigned short q[8];
#pragma unroll
  for (int i = 0; i < 8; ++i) {
    const float v = W1[(size_t)(kbase + i) * H + col];
    const __half hh = __float2half(v);                 // RTN
    q[i] = __half_as_ushort(hh);
  }
  uint4 h4;
  h4.x = (unsigned)q[0] | ((unsigned)q[1] << 16);
  h4.y = (unsigned)q[2] | ((unsigned)q[3] << 16);
  h4.z = (unsigned)q[4] | ((unsigned)q[5] << 16);
  h4.w = (unsigned)q[6] | ((unsigned)q[7] << 16);
  pw[g] = h4;
}

// ---- Persistent fused kernel ----------------------------------------------
// 256 blocks x 512 threads (8 waves: 2 row-halves x 4 col-groups), 1 block/CU.
// W: entire fp16 fragment set (64 KB) in LDS once -> k-loop is pure LDS+MFMA.
// x: per 32-row tile, reg-staged (4 float4/thread) at iteration TOP, written
// to LDS (fp16 frag-plane layout) at iteration BOTTOM -> 32 KB/tile in flight
// under the whole body = continuous HBM streaming. Pool phase re-reads own
// rows fp32 from global (L2-hot).
extern "C" __global__ void __launch_bounds__(512, 2)
k_fused(const float* __restrict__ x, const int* __restrict__ batch,
        const uint4* __restrict__ pw, const float* __restrict__ b1,
        const float* __restrict__ W2, const float* __restrict__ b2,
        float* __restrict__ out, float* __restrict__ zacc, int N)
{
  __shared__ uint4 wfrag[4096];        // 64 KB: W fp16 frags, (c*8+ht)*64+l
  __shared__ uint2 xbuf[2][2048];      // 2 x 16 KB: A-planes (c*2+rg)*1KB
  __shared__ float sred[4][BM];
  __shared__ float wlds[BM];

  const int t = threadIdx.x;
  const int l = t & 63;
  const int w = t >> 6;        // wave 0..7
  const int lg = l >> 4;       // k-group / C-row quad
  const int lr = l & 15;       // A M-row / B,C N-col
  const int rg = w >> 2;       // row half (0..1)
  const int cg = w & 3;        // col group (0..3)

  // hoisted epilogue constants (oldest in vmcnt stream)
  float bvv[2], wvv[2];
#pragma unroll
  for (int h = 0; h < 2; ++h) {
    const int col = cg * 32 + h * 16 + lr;
    bvv[h] = b1[col];
    wvv[h] = W2[col];
  }
  const float b2v = b2[0];

  // ---- prologue: W -> LDS; first x tile -> regs -> LDS buf0 ----------------
  const char* pwb = (const char*)pw;
#pragma unroll
  for (int i = 0; i < 8; ++i) {
    const int off = i * 8192 + t * 16;      // wave-uniform base + lane*16
    gload16(pwb + off, (char*)wfrag + off);
  }

  // x tile loaders: thread t covers row r = t>>4, cols (t&15)*4 + i*64
  const int xr = t >> 4;                    // 0..31
  const int xc0 = (t & 15) * 4;
  const int xlgw = (t & 7) >> 1;            // frag k-group of this thread's cols
  const int xlane = xlgw * 16 + (xr & 15);
  const int xp = t & 1;                     // 8B half of the 16B lane slot
  const int xkslo = (t >> 3) & 1;           // kstep low bit
  const int xstripe = xr >> 4;

  float4 stage[4];
  auto XLOAD = [&](int j) {
    const float* base = x + (size_t)j * BM * D + (size_t)xr * D + xc0;
#pragma unroll
    for (int i = 0; i < 4; ++i)
      stage[i] = *reinterpret_cast<const float4*>(base + i * 64);
  };
  auto XSTORE = [&](int buf) {
    uint2* dst = &xbuf[buf][0];
#pragma unroll
    for (int i = 0; i < 4; ++i) {
      const int kst = i * 2 + xkslo;
      const int plane = kst * 2 + xstripe;
      uint2 d;
      d.x = pkrtz(stage[i].x, stage[i].y);
      d.y = pkrtz(stage[i].z, stage[i].w);
      dst[plane * 128 + xlane * 2 + xp] = d;
    }
  };

  XLOAD(blockIdx.x);
  XSTORE(0);                 // compiler-inserted vmcnt covers W copy too
  __syncthreads();

  const int NT = (N + BM - 1) / BM;
  int buf = 0;
#pragma unroll 1
  for (int j = blockIdx.x; j < NT; j += NBLK) {
    const int jn = j + NBLK;
    if (jn < NT) XLOAD(jn);                       // issue next tile early
    __builtin_amdgcn_sched_barrier(0);            // pin issue point

    // ---- compute: pure LDS + MFMA ------------------------------------------
    f32x4 acc0 = {}, acc1 = {};
#pragma unroll
    for (int c = 0; c < KSTEPS; ++c) {
      FragH a, bf0, bf1;
      a.u = *reinterpret_cast<const uint4*>(&xbuf[buf][(c * 2 + rg) * 128 + l * 2]);
      bf0.u = wfrag[(c * 8 + cg * 2 + 0) * 64 + l];
      bf1.u = wfrag[(c * 8 + cg * 2 + 1) * 64 + l];
      acc0 = __builtin_amdgcn_mfma_f32_16x16x32_f16(a.f, bf0.f, acc0, 0, 0, 0);
      acc1 = __builtin_amdgcn_mfma_f32_16x16x32_f16(a.f, bf1.f, acc1, 0, 0, 0);
    }

    // ---- epilogue: relu(h+b1)@W2 partials -> sred -> wlds = exp(score) -----
#pragma unroll
    for (int r = 0; r < 4; ++r) {
      float p = fmaf(fmaxf(acc0[r] + bvv[0], 0.0f), wvv[0],
               fmaf(fmaxf(acc1[r] + bvv[1], 0.0f), wvv[1], 0.0f));
#pragma unroll
      for (int off = 1; off < 16; off <<= 1) p += __shfl_xor(p, off, 64);
      if (lr == 0) sred[cg][rg * 16 + lg * 4 + r] = p;
    }
    __syncthreads();
    if (w == 0) {
      const int row = l & 31;
      const int node = j * BM + row;
      const float sc = sred[0][row] + sred[1][row] + sred[2][row] + sred[3][row] + b2v;
      const float wgt = (l < 32 && node < N) ? __expf(sc) : 0.0f;
      if (l < 32) wlds[row] = wgt;
      float zs = wgt;
#pragma unroll
      for (int off = 1; off < 64; off <<= 1) zs += __shfl_xor(zs, off, 64);
      if (l == 0) atomicAdd(zacc, zs);
    }
    __syncthreads();

    // ---- pooling: wave w owns rows j*32 + w*4 .. +3 (L2-hot re-read) -------
    {
      const int nStart = j * BM + w * 4;
      if (nStart < N) {
        const int nEnd = min(nStart + 4, N);
        float4 a4 = make_float4(0.f, 0.f, 0.f, 0.f);
        int bprev = batch[nStart];
#pragma unroll 1
        for (int n = nStart; n < nEnd; ++n) {
          const int b = batch[n];
          if (b != bprev) {
            float* o = out + (size_t)bprev * D + l * 4;
            atomicAdd(o + 0, a4.x); atomicAdd(o + 1, a4.y);
            atomicAdd(o + 2, a4.z); atomicAdd(o + 3, a4.w);
            a4 = make_float4(0.f, 0.f, 0.f, 0.f);
            bprev = b;
          }
          const float wgt = wlds[n - j * BM];
          const float4 xv = *reinterpret_cast<const float4*>(x + (size_t)n * D + l * 4);
          a4.x = fmaf(xv.x, wgt, a4.x);
          a4.y = fmaf(xv.y, wgt, a4.y);
          a4.z = fmaf(xv.z, wgt, a4.z);
          a4.w = fmaf(xv.w, wgt, a4.w);
        }
        float* o = out + (size_t)bprev * D + l * 4;
        atomicAdd(o + 0, a4.x); atomicAdd(o + 1, a4.y);
        atomicAdd(o + 2, a4.z); atomicAdd(o + 3, a4.w);
      }
    }

    // ---- write next tile into the other buffer (loads have had ~full body)
    if (jn < NT) XSTORE(buf ^ 1);
    __syncthreads();
    buf ^= 1;
  }
}

// ---- finish: out *= 1/Z ----------------------------------------------------
extern "C" __global__ void __launch_bounds__(256)
k_finish(float* __restrict__ out, const float* __restrict__ zacc, int size)
{
  const int i = blockIdx.x * 256 + threadIdx.x;
  if (i < size) out[i] *= (1.0f / *zacc);
}

extern "C" void kernel_launch(void* const* d_in, const int* in_sizes, int n_in,
                              void* d_out, int out_size, void* d_ws, size_t ws_size,
                              hipStream_t stream)
{
  const float* x     = (const float*)d_in[0];
  const int*   batch = (const int*)d_in[1];
  const float* W1 = (const float*)d_in[3];
  const float* b1 = (const float*)d_in[4];
  const float* W2 = (const float*)d_in[5];
  const float* b2 = (const float*)d_in[6];
  const int N = in_sizes[1];

  float* zacc = (float*)d_ws;
  uint4* pw   = (uint4*)((char*)d_ws + 256);            // 64 KB fp16 W frags

  k_init<<<(out_size + 255) / 256, 256, 0, stream>>>((float*)d_out, out_size, zacc);
  k_pack<<<16, 256, 0, stream>>>(W1, pw);

  k_fused<<<NBLK, 512, 0, stream>>>(x, batch, pw, b1, W2, b2,
                                    (float*)d_out, zacc, N);

  k_finish<<<(out_size + 255) / 256, 256, 0, stream>>>((float*)d_out, zacc, out_size);
}

// Round 16
// 174.587 us; speedup vs baseline: 2.3466x; 2.3466x over previous
//
#include <hip/hip_runtime.h>
#include <hip/hip_fp16.h>
#include <math.h>

typedef __attribute__((ext_vector_type(8))) _Float16 f16x8;
typedef __attribute__((ext_vector_type(2))) __fp16 fp16x2;
typedef __attribute__((ext_vector_type(4))) float f32x4;

constexpr int D = 256;           // feature dim (K of GEMM)
constexpr int H = 128;           // hidden dim
constexpr int KSTEPS = D / 32;   // 8 MFMA k-steps
constexpr int BM = 128;          // rows per block

union FragH { uint4 u; f16x8 f; };
union H2U { fp16x2 h; unsigned int u; };

__device__ __forceinline__ unsigned int pkrtz(float a, float b) {
  H2U r; r.h = __builtin_amdgcn_cvt_pkrtz(a, b); return r.u;
}
__device__ __forceinline__ void gload16(const void* g, void* l) {
  __builtin_amdgcn_global_load_lds(
      (const __attribute__((address_space(1))) unsigned int*)g,
      (__attribute__((address_space(3))) unsigned int*)l, 16, 0, 0);
}
__device__ __forceinline__ void block_sync() {
  asm volatile("" ::: "memory");
  __builtin_amdgcn_s_barrier();
  asm volatile("" ::: "memory");
}

// ---- init: zero d_out + Z accumulator --------------------------------------
extern "C" __global__ void __launch_bounds__(256)
k_init(float* __restrict__ out, int out_size, float* __restrict__ zacc)
{
  const int i = blockIdx.x * 256 + threadIdx.x;
  if (i < out_size) out[i] = 0.0f;
  if (i == 0) *zacc = 0.0f;
}

// ---- Pre-pack W1 into per-lane MFMA B-fragment order (fp16 RTN) ------------
// Index g = (kstep*8 + htile)*64 + lane; element j: K = kstep*32+(lane>>4)*8+j,
// N(col) = htile*16 + (lane&15).
extern "C" __global__ void __launch_bounds__(256)
k_pack(const float* __restrict__ W1, uint4* __restrict__ pw)
{
  const int g = blockIdx.x * 256 + threadIdx.x;       // 0..4095
  const int c = g >> 9, ht = (g >> 6) & 7, l = g & 63;
  const int kbase = c * 32 + (l >> 4) * 8;
  const int col = ht * 16 + (l & 15);
  unsigned short q[8];
#pragma unroll
  for (int i = 0; i < 8; ++i) {
    const float v = W1[(size_t)(kbase + i) * H + col];
    const __half hh = __float2half(v);                 // RTN
    q[i] = __half_as_ushort(hh);
  }
  uint4 h4;
  h4.x = (unsigned)q[0] | ((unsigned)q[1] << 16);
  h4.y = (unsigned)q[2] | ((unsigned)q[3] << 16);
  h4.z = (unsigned)q[4] | ((unsigned)q[5] << 16);
  h4.w = (unsigned)q[6] | ((unsigned)q[7] << 16);
  pw[g] = h4;
}

// ---- Fused: scores (fp16 MFMA) -> w = exp(s) -> weighted pool (R11 base) ---
// 4 waves (2x2): wave (rg,cg) computes rows rg*64..+63 x hidden cols cg*64..+63.
// Per-kstep issue order: [B(c+1) reg loads (L2)] -> [STAGE(c+1) gload_lds]
// -> vmcnt(8) (drains B(c)+STAGE(c), both issued ONE KSTEP EARLIER -> their
// latency is hidden under kstep c-1's MFMA phase; nothing waited on at the
// barrier was issued this kstep).
extern "C" __global__ void __launch_bounds__(256, 3)
k_fused(const float* __restrict__ x, const int* __restrict__ batch,
        const uint4* __restrict__ pw, const float* __restrict__ b1,
        const float* __restrict__ W2, const float* __restrict__ b2,
        float* __restrict__ out, float* __restrict__ zacc, int N)
{
  __shared__ float4 xplane[2][1024];   // 16 planes x 64 lanes x 16 B = 16 KB/buf
  __shared__ float sred[2][BM];        // cross-wave epilogue partials
  __shared__ float wlds[BM];           // per-row unnormalized weights

  const int t = threadIdx.x;
  const int l = t & 63;
  const int w = t >> 6;
  const int lg = l >> 4;      // k-group (0..3)
  const int lr = l & 15;      // M-row (A) / N-col (B,C)
  const int rg = w >> 1;      // row half (0..1)
  const int cg = w & 1;       // col half (0..1)
  const int n0 = blockIdx.x * BM;

  const char* xb = (const char*)x;

  // hoisted epilogue constants (issued before the main vmcnt stream matters)
  float bvv[4], wvv[4];
#pragma unroll
  for (int h = 0; h < 4; ++h) {
    const int col = (cg * 4 + h) * 16 + lr;
    bvv[h] = b1[col];
    wvv[h] = W2[col];
  }
  const float b2v = b2[0];

  // stage x tile for kstep c into buffer buf (4 gload16 per thread)
  auto STAGE = [&](int buf, int c) {
#pragma unroll
    for (int i = 0; i < 4; ++i) {
      const int plane = i * 4 + w;
      const int g = plane >> 1, p = plane & 1;
      const int srow = min(n0 + g * 16 + lr, N - 1);   // clamp OOB (discarded)
      gload16(xb + (size_t)srow * 1024 + c * 128 + lg * 32 + p * 16,
              (char*)&xplane[buf][plane * 64 + l]);
    }
  };

  f32x4 acc[4][4] = {};   // [stripe s][local htile h]

  // prologue: B(0) regs, then STAGE(0)
  FragH bw[4], nbw[4];
#pragma unroll
  for (int h = 0; h < 4; ++h)
    bw[h].u = pw[(cg * 4 + h) * 64 + l];
  STAGE(0, 0);

#pragma unroll 1
  for (int c = 0; c < KSTEPS; ++c) {
    const int cur = c & 1;
    if (c + 1 < KSTEPS) {
      // issue NEXT kstep's B regs first (L2), then next x stage (HBM)
#pragma unroll
      for (int h = 0; h < 4; ++h)
        nbw[h].u = pw[((c + 1) * 8 + cg * 4 + h) * 64 + l];
      STAGE(cur ^ 1, c + 1);
      // outstanding: B(c):4 + S(c):4 + B(c+1):4 + S(c+1):4 = 16
      // vmcnt(8) drains B(c)+S(c) (issued one kstep ago), keeps (c+1) in flight
      asm volatile("s_waitcnt vmcnt(8)" ::: "memory");
    } else {
      asm volatile("s_waitcnt vmcnt(0)" ::: "memory");
    }
    block_sync();

    // A fragments per stripe (conflict-free plane reads) -> fp16, MFMA
#pragma unroll
    for (int s = 0; s < 4; ++s) {
      const int g = rg * 4 + s;
      const float4 u0 = xplane[cur][(g * 2 + 0) * 64 + l];
      const float4 u1 = xplane[cur][(g * 2 + 1) * 64 + l];
      FragH a;
      a.u.x = pkrtz(u0.x, u0.y);
      a.u.y = pkrtz(u0.z, u0.w);
      a.u.z = pkrtz(u1.x, u1.y);
      a.u.w = pkrtz(u1.z, u1.w);
#pragma unroll
      for (int h = 0; h < 4; ++h)
        acc[s][h] = __builtin_amdgcn_mfma_f32_16x16x32_f16(a.f, bw[h].f, acc[s][h], 0, 0, 0);
    }
    block_sync();   // all reads of buf[cur] done before it is restaged
#pragma unroll
    for (int h = 0; h < 4; ++h) bw[h] = nbw[h];
  }

  // ---- epilogue: relu(h+b1)@W2 partials, cross-wave sum, w = exp(s) --------
#pragma unroll
  for (int s = 0; s < 4; ++s) {
#pragma unroll
    for (int r = 0; r < 4; ++r) {
      float p = 0.0f;
#pragma unroll
      for (int h = 0; h < 4; ++h)
        p = fmaf(fmaxf(acc[s][h][r] + bvv[h], 0.0f), wvv[h], p);
#pragma unroll
      for (int off = 1; off < 16; off <<= 1) p += __shfl_xor(p, off, 64);
      if (lr == 0) sred[cg][rg * 64 + s * 16 + lg * 4 + r] = p;
    }
  }
  __syncthreads();
  if (cg == 0) {                      // waves 0 and 2 finalize 64 rows each
    const int row = rg * 64 + l;
    const int node = n0 + row;
    const float sc = sred[0][row] + sred[1][row] + b2v;
    const float wgt = (node < N) ? __expf(sc) : 0.0f;
    wlds[row] = wgt;
    float zs = wgt;
#pragma unroll
    for (int off = 1; off < 64; off <<= 1) zs += __shfl_xor(zs, off, 64);
    if (l == 0) atomicAdd(zacc, zs);
  }
  __syncthreads();

  // ---- phase 2: pool own 128 rows (batch sorted); lane owns 4 columns ----
  {
    const int nStart = n0 + w * 32;
    const int nEnd = min(nStart + 32, N);
    if (nStart < nEnd) {
      float4 a4 = make_float4(0.f, 0.f, 0.f, 0.f);
      int bprev = batch[nStart];
      for (int n = nStart; n < nEnd; ++n) {
        const int b = batch[n];
        if (b != bprev) {
          float* o = out + (size_t)bprev * D + l * 4;
          atomicAdd(o + 0, a4.x); atomicAdd(o + 1, a4.y);
          atomicAdd(o + 2, a4.z); atomicAdd(o + 3, a4.w);
          a4 = make_float4(0.f, 0.f, 0.f, 0.f);
          bprev = b;
        }
        const float wgt = wlds[n - n0];
        const float4 xv = *reinterpret_cast<const float4*>(x + (size_t)n * D + l * 4);
        a4.x = fmaf(xv.x, wgt, a4.x);
        a4.y = fmaf(xv.y, wgt, a4.y);
        a4.z = fmaf(xv.z, wgt, a4.z);
        a4.w = fmaf(xv.w, wgt, a4.w);
      }
      float* o = out + (size_t)bprev * D + l * 4;
      atomicAdd(o + 0, a4.x); atomicAdd(o + 1, a4.y);
      atomicAdd(o + 2, a4.z); atomicAdd(o + 3, a4.w);
    }
  }
}

// ---- finish: out *= 1/Z ----------------------------------------------------
extern "C" __global__ void __launch_bounds__(256)
k_finish(float* __restrict__ out, const float* __restrict__ zacc, int size)
{
  const int i = blockIdx.x * 256 + threadIdx.x;
  if (i < size) out[i] *= (1.0f / *zacc);
}

extern "C" void kernel_launch(void* const* d_in, const int* in_sizes, int n_in,
                              void* d_out, int out_size, void* d_ws, size_t ws_size,
                              hipStream_t stream)
{
  const float* x     = (const float*)d_in[0];
  const int*   batch = (const int*)d_in[1];
  const float* W1 = (const float*)d_in[3];
  const float* b1 = (const float*)d_in[4];
  const float* W2 = (const float*)d_in[5];
  const float* b2 = (const float*)d_in[6];
  const int N = in_sizes[1];

  float* zacc = (float*)d_ws;
  uint4* pw   = (uint4*)((char*)d_ws + 256);            // 64 KB fp16 W frags

  k_init<<<(out_size + 255) / 256, 256, 0, stream>>>((float*)d_out, out_size, zacc);
  k_pack<<<16, 256, 0, stream>>>(W1, pw);

  const int g1 = (N + BM - 1) / BM;
  k_fused<<<g1, 256, 0, stream>>>(x, batch, pw, b1, W2, b2,
                                  (float*)d_out, zacc, N);

  k_finish<<<(out_size + 255) / 256, 256, 0, stream>>>((float*)d_out, zacc, out_size);
}